// Round 4
// baseline (263.148 us; speedup 1.0000x reference)
//
#include <hip/hip_runtime.h>

// ws layout (floats):
//   [128..202]       quantized w_conv (75)
//   [256..44159]     quantized w_fc1 TRANSPOSED [j=343][o=128]
//   [44160..44671]   quantized w_fc2 [4][128]
#define WS_WCONV   128
#define WS_W1T     256
#define WS_W2      44160

__device__ __forceinline__ float q4(float w, float s) {
  if (s <= 0.f) return 0.f;
  float r = rintf(w / s);                     // round-half-even == jnp.round
  r = fminf(fmaxf(r, -8.f), 7.f);
  return r * s;
}

// Single quant dispatch (R3-proven, absmax 0): every fc1 block redundantly
// computes global max|w1| (172 KB, L2/LLC-cheap). Block 88: conv + fc2.
__global__ __launch_bounds__(256) void quant_all(
    const float* __restrict__ wconv, const float* __restrict__ w1,
    const float* __restrict__ w2, float* __restrict__ ws) {
  __shared__ float red[256];
  int b = blockIdx.x, t = threadIdx.x;
  if (b < 88) {
    const float4* w4 = (const float4*)w1;     // 43904/4 == 10976
    float m = 0.f;
    for (int i = t; i < 10976; i += 256) {
      float4 v = w4[i];
      m = fmaxf(m, fmaxf(fmaxf(fabsf(v.x), fabsf(v.y)),
                         fmaxf(fabsf(v.z), fabsf(v.w))));
    }
    red[t] = m;
    __syncthreads();
    for (int s = 128; s > 0; s >>= 1) {
      if (t < s) red[t] = fmaxf(red[t], red[t + s]);
      __syncthreads();
    }
    float s = red[0] * (1.0f / 7.0f);
    #pragma unroll
    for (int k = 0; k < 2; ++k) {
      int idx = b * 512 + k * 256 + t;
      if (idx < 43904) {
        float q = q4(w1[idx], s);
        int o = idx / 343;
        int j = idx - o * 343;
        ws[WS_W1T + j * 128 + o] = q;         // transpose for coalesced FC1
      }
    }
  } else {
    float mc = (t < 75) ? fabsf(wconv[t]) : 0.f;
    float m2 = 0.f;
    for (int i = t; i < 512; i += 256) m2 = fmaxf(m2, fabsf(w2[i]));
    red[t] = mc;
    __syncthreads();
    for (int s = 128; s > 0; s >>= 1) {
      if (t < s) red[t] = fmaxf(red[t], red[t + s]);
      __syncthreads();
    }
    float sc = red[0] * (1.0f / 7.0f);
    __syncthreads();
    red[t] = m2;
    __syncthreads();
    for (int s = 128; s > 0; s >>= 1) {
      if (t < s) red[t] = fmaxf(red[t], red[t + s]);
      __syncthreads();
    }
    float s2 = red[0] * (1.0f / 7.0f);
    if (t < 75) ws[WS_WCONV + t] = q4(wconv[t], sc);
    #pragma unroll
    for (int k = 0; k < 2; ++k) {
      int idx = k * 256 + t;
      ws[WS_W2 + idx] = q4(w2[idx], s2);
    }
  }
}

// Conv (R3-proven math, stride-31 flat layout over the FULL 31-depth x).
// One pooled output per thread t<343: pd = t/49.
__device__ __forceinline__ void conv_all(
    const float* __restrict__ xs, const float* __restrict__ wq,
    int t, float bc, float* __restrict__ feat) {
  if (t >= 343) return;
  int pdl = t / 49;
  int rr  = t - pdl * 49;
  int ph  = rr / 7;
  int pw  = rr - ph * 7;
  float c[2][2][2];                           // [odp][ohp][owp]
  #pragma unroll
  for (int i = 0; i < 8; ++i) ((float*)c)[i] = 0.f;
  int base0 = pdl * 1984 + ph * 62 + pw * 4;  // 1984 = 4*496, 62 = 2*31
  #pragma unroll
  for (int dd = 0; dd < 7; ++dd) {
    int rbase = base0 + dd * 496;
    #pragma unroll
    for (int hh = 0; hh < 4; ++hh) {
      float row[7];
      #pragma unroll
      for (int wi = 0; wi < 7; ++wi) row[wi] = xs[rbase + hh * 31 + wi];
      #pragma unroll
      for (int odp = 0; odp < 2; ++odp) {
        int kd = dd - 2 * odp;
        if (kd < 0 || kd > 4) continue;       // folds at compile time
        #pragma unroll
        for (int ohp = 0; ohp < 2; ++ohp) {
          int kh = hh - ohp;
          if (kh < 0 || kh > 2) continue;     // folds at compile time
          #pragma unroll
          for (int owp = 0; owp < 2; ++owp) {
            float a = c[odp][ohp][owp];
            #pragma unroll
            for (int kw = 0; kw < 5; ++kw)
              a = fmaf(row[2 * owp + kw], wq[kd * 15 + kh * 5 + kw], a);
            c[odp][ohp][owp] = a;
          }
        }
      }
    }
  }
  float m = ((float*)c)[0];
  #pragma unroll
  for (int i = 1; i < 8; ++i) m = fmaxf(m, ((float*)c)[i]);
  feat[pdl * 49 + rr] = m + bc;
}

// Fully fused, restructured: stage the ENTIRE 61.5 KB x with one coalesced
// float4 copy burst (load->store pairs, no held register arrays -> no spill),
// 1 barrier, ALL conv in one phase (343 of 384 threads), then FC1/FC2/softmax
// (identical math to R0). LDS 62.9 KB -> 2 blocks/CU x 6 waves = 12 waves/CU;
// the co-resident block computes while this block's staging burst is in
// flight. Barriers per block: 11 -> 5.
__global__ __launch_bounds__(384) void fused_net(
    const float* __restrict__ x, const float* __restrict__ bconv,
    const float* __restrict__ ws, const float* __restrict__ bfc1,
    const float* __restrict__ bfc2, float* __restrict__ out) {
  __shared__ alignas(16) float xs[15376];     // full 31 depths * 496
  __shared__ alignas(16) float feat[344];     // +1: feat[343]=0 pads FC1 quads
  float* fc1p = xs;                           // alias: live only after conv
  float* a1   = xs + 128;
  float* s2   = xs + 256;
  int t = threadIdx.x;
  int b = blockIdx.x;
  const float* wq = ws + WS_WCONV;
  float bc = bconv[0];

  // P0: stage whole x (3844 float4) -> xs, coalesced; no registers held
  // across the barrier (each load feeds its store immediately).
  {
    const float4* src = (const float4*)(x + (size_t)b * 15376);
    float4* dst = (float4*)xs;
    for (int i = t; i < 3844; i += 384) dst[i] = src[i];
    if (t == 0) feat[343] = 0.f;
  }
  __syncthreads();

  // P1: conv+pool, all 343 pooled outputs in one phase
  conv_all(xs, wq, t, bc, feat);
  __syncthreads();

  // P2: FC1 (343->128) on t<256, exact R0 math (halves at j=172; g=1 tail
  // uses feat[343]=0, w1T row 343 lands in finite W2 region * 0.0 -> exact).
  int g = (t >> 7) & 1, o = t & 127;
  float acc = 0.f;
  if (t < 256) {
    const float* w1T = ws + WS_W1T;
    int j0 = g ? 172 : 0;
    const float4* f4 = (const float4*)&feat[j0];
    const float* wp = w1T + j0 * 128 + o;
    float q0 = 0.f, q1 = 0.f, q2 = 0.f, q3 = 0.f;
    for (int q = 0; q < 43; ++q) {
      float4 ff = f4[q];
      q0 = fmaf(ff.x, wp[0],   q0);
      q1 = fmaf(ff.y, wp[128], q1);
      q2 = fmaf(ff.z, wp[256], q2);
      q3 = fmaf(ff.w, wp[384], q3);
      wp += 512;
    }
    acc = (q0 + q1) + (q2 + q3);
    if (g) fc1p[o] = acc;
  }
  __syncthreads();
  if (t < 256 && !g) a1[o] = fmaxf(acc + fc1p[o] + bfc1[o], 0.f);
  __syncthreads();

  // P3: FC2 (128->4) on one wave: lane = (kk,cls), shuffle-reduce over kk.
  if (t < 64) {
    int cls = t & 3, kk = t >> 2;             // kk 0..15, 8 k's each
    const float* w2p = ws + WS_W2 + cls * 128 + kk * 8;
    const float* av = a1 + kk * 8;
    float p = 0.f;
    #pragma unroll
    for (int i = 0; i < 8; ++i) p = fmaf(av[i], w2p[i], p);
    p += __shfl_down(p, 32);
    p += __shfl_down(p, 16);
    p += __shfl_down(p, 8);
    p += __shfl_down(p, 4);
    if (t < 4) s2[t] = p + bfc2[t];
  }
  __syncthreads();
  // P4: softmax + store
  if (t < 4) {
    float v0 = s2[0], v1 = s2[1], v2 = s2[2], v3 = s2[3];
    float m = fmaxf(fmaxf(v0, v1), fmaxf(v2, v3));
    float e0 = expf(v0 - m), e1 = expf(v1 - m);
    float e2 = expf(v2 - m), e3 = expf(v3 - m);
    float inv = 1.f / (e0 + e1 + e2 + e3);
    float mine = (t == 0) ? e0 : (t == 1) ? e1 : (t == 2) ? e2 : e3;
    out[b * 4 + t] = mine * inv;
  }
}

extern "C" void kernel_launch(void* const* d_in, const int* in_sizes, int n_in,
                              void* d_out, int out_size, void* d_ws, size_t ws_size,
                              hipStream_t stream) {
  const float* x     = (const float*)d_in[0];
  const float* wconv = (const float*)d_in[1];
  const float* bconv = (const float*)d_in[2];
  const float* wfc1  = (const float*)d_in[3];
  const float* bfc1  = (const float*)d_in[4];
  const float* wfc2  = (const float*)d_in[5];
  const float* bfc2  = (const float*)d_in[6];
  float* out = (float*)d_out;
  float* ws  = (float*)d_ws;

  quant_all<<<89, 256, 0, stream>>>(wconv, wfc1, wfc2, ws);
  fused_net<<<2048, 384, 0, stream>>>(x, bconv, ws, bfc1, bfc2, out);
}

// Round 5
// 234.897 us; speedup vs baseline: 1.1203x; 1.1203x over previous
//
#include <hip/hip_runtime.h>

// ws layout (floats):
//   [128..202]       quantized w_conv (75)
//   [256..44159]     quantized w_fc1 TRANSPOSED [j=343][o=128]
//   [44160..44671]   quantized w_fc2 [4][128]
#define WS_WCONV   128
#define WS_W1T     256
#define WS_W2      44160

__device__ __forceinline__ float q4(float w, float s) {
  if (s <= 0.f) return 0.f;
  float r = rintf(w / s);                     // round-half-even == jnp.round
  r = fminf(fmaxf(r, -8.f), 7.f);
  return r * s;
}

// Single quant dispatch (R3-proven, absmax 0): every fc1 block redundantly
// computes global max|w1| (172 KB, L2/LLC-cheap). Block 88: conv + fc2.
__global__ __launch_bounds__(256) void quant_all(
    const float* __restrict__ wconv, const float* __restrict__ w1,
    const float* __restrict__ w2, float* __restrict__ ws) {
  __shared__ float red[256];
  int b = blockIdx.x, t = threadIdx.x;
  if (b < 88) {
    const float4* w4 = (const float4*)w1;     // 43904/4 == 10976
    float m = 0.f;
    for (int i = t; i < 10976; i += 256) {
      float4 v = w4[i];
      m = fmaxf(m, fmaxf(fmaxf(fabsf(v.x), fabsf(v.y)),
                         fmaxf(fabsf(v.z), fabsf(v.w))));
    }
    red[t] = m;
    __syncthreads();
    for (int s = 128; s > 0; s >>= 1) {
      if (t < s) red[t] = fmaxf(red[t], red[t + s]);
      __syncthreads();
    }
    float s = red[0] * (1.0f / 7.0f);
    #pragma unroll
    for (int k = 0; k < 2; ++k) {
      int idx = b * 512 + k * 256 + t;
      if (idx < 43904) {
        float q = q4(w1[idx], s);
        int o = idx / 343;
        int j = idx - o * 343;
        ws[WS_W1T + j * 128 + o] = q;         // transpose for coalesced FC1
      }
    }
  } else {
    float mc = (t < 75) ? fabsf(wconv[t]) : 0.f;
    float m2 = 0.f;
    for (int i = t; i < 512; i += 256) m2 = fmaxf(m2, fabsf(w2[i]));
    red[t] = mc;
    __syncthreads();
    for (int s = 128; s > 0; s >>= 1) {
      if (t < s) red[t] = fmaxf(red[t], red[t + s]);
      __syncthreads();
    }
    float sc = red[0] * (1.0f / 7.0f);
    __syncthreads();
    red[t] = m2;
    __syncthreads();
    for (int s = 128; s > 0; s >>= 1) {
      if (t < s) red[t] = fmaxf(red[t], red[t + s]);
      __syncthreads();
    }
    float s2 = red[0] * (1.0f / 7.0f);
    if (t < 75) ws[WS_WCONV + t] = q4(wconv[t], sc);
    #pragma unroll
    for (int k = 0; k < 2; ++k) {
      int idx = k * 256 + t;
      ws[WS_W2 + idx] = q4(w2[idx], s2);
    }
  }
}

// Conv inner phase (R0-proven math, stride-31 flat layout). npf threads,
// pd = pd_off + t/49. xs holds an 11-depth chunk; local depth = 4*(t/49)+dd.
__device__ __forceinline__ void conv_phase(
    const float* __restrict__ xs, const float* __restrict__ wq,
    int t, int npf, int pd_off, float bc, float* __restrict__ feat) {
  if (t >= npf) return;
  int pdl = t / 49;
  int rr  = t - pdl * 49;
  int ph  = rr / 7;
  int pw  = rr - ph * 7;
  float c[2][2][2];                           // [odp][ohp][owp]
  #pragma unroll
  for (int i = 0; i < 8; ++i) ((float*)c)[i] = 0.f;
  int base0 = pdl * 1984 + ph * 62 + pw * 4;  // 1984 = 4*496, 62 = 2*31
  #pragma unroll
  for (int dd = 0; dd < 7; ++dd) {
    int rbase = base0 + dd * 496;
    #pragma unroll
    for (int hh = 0; hh < 4; ++hh) {
      float row[7];
      #pragma unroll
      for (int wi = 0; wi < 7; ++wi) row[wi] = xs[rbase + hh * 31 + wi];
      #pragma unroll
      for (int odp = 0; odp < 2; ++odp) {
        int kd = dd - 2 * odp;
        if (kd < 0 || kd > 4) continue;       // folds at compile time
        #pragma unroll
        for (int ohp = 0; ohp < 2; ++ohp) {
          int kh = hh - ohp;
          if (kh < 0 || kh > 2) continue;     // folds at compile time
          #pragma unroll
          for (int owp = 0; owp < 2; ++owp) {
            float a = c[odp][ohp][owp];
            #pragma unroll
            for (int kw = 0; kw < 5; ++kw)
              a = fmaf(row[2 * owp + kw], wq[kd * 15 + kh * 5 + kw], a);
            c[odp][ohp][owp] = a;
          }
        }
      }
    }
  }
  float m = ((float*)c)[0];
  #pragma unroll
  for (int i = 1; i < 8; ++i) m = fmaxf(m, ((float*)c)[i]);
  feat[(pdl + pd_off) * 49 + rr] = m + bc;
}

// Fully fused: conv+pool over FOUR 11-depth chunks (23.2 KB LDS -> 6
// blocks/CU = 24 waves, 2x R0's wave-parallelism) + FC1 + FC2 + softmax.
// Staging is plain load->store float4 (NO register-held arrays -> no spill;
// R1/R2 both died to spills from reg-prefetch). One block per batch; the
// 5 co-resident blocks fill each other's barrier/memory stalls.
__global__ __launch_bounds__(256, 4) void fused_net(
    const float* __restrict__ x, const float* __restrict__ bconv,
    const float* __restrict__ ws, const float* __restrict__ bfc1,
    const float* __restrict__ bfc2, float* __restrict__ out) {
  __shared__ alignas(16) float xs[5456];      // 11 depths * 496
  __shared__ alignas(16) float feat[344];     // +1: feat[343]=0 pads FC1 quads
  float* fc1p = xs;                           // alias: live only after conv
  float* a1   = xs + 128;
  float* s2   = xs + 256;
  int t = threadIdx.x;
  int b = blockIdx.x;
  const float* wq = ws + WS_WCONV;
  float bc = bconv[0];
  const float4* xb4 = (const float4*)(x + (size_t)b * 15376);
  float4* dst = (float4*)xs;

  // C0: stage depths 0..10 (1364 f4), conv pd 0,1
  for (int i = t; i < 1364; i += 256) dst[i] = xb4[i];
  if (t == 0) feat[343] = 0.f;
  __syncthreads();
  conv_phase(xs, wq, t, 98, 0, bc, feat);
  __syncthreads();

  // C1: stage depths 8..18 (f4 base 8*124=992), conv pd 2,3
  for (int i = t; i < 1364; i += 256) dst[i] = xb4[992 + i];
  __syncthreads();
  conv_phase(xs, wq, t, 98, 2, bc, feat);
  __syncthreads();

  // C2: stage depths 16..26 (base 1984), conv pd 4,5
  for (int i = t; i < 1364; i += 256) dst[i] = xb4[1984 + i];
  __syncthreads();
  conv_phase(xs, wq, t, 98, 4, bc, feat);
  __syncthreads();

  // C3: stage depths 24..30 (base 2976, 868 f4), conv pd 6
  for (int i = t; i < 868; i += 256) dst[i] = xb4[2976 + i];
  __syncthreads();
  conv_phase(xs, wq, t, 49, 6, bc, feat);
  __syncthreads();

  // FC1 (343->128). g = j-half, o = output. Features read as b128 quads
  // (43 quads each half; g=1 tail uses feat[343]=0, w1T row 343 lands in
  // finite W2 region * 0.0 -> exact). w1T loads lane-coalesced.
  int g = t >> 7, o = t & 127;
  {
    const float* w1T = ws + WS_W1T;
    int j0 = g ? 172 : 0;
    const float4* f4 = (const float4*)&feat[j0];
    const float* wp = w1T + j0 * 128 + o;
    float q0 = 0.f, q1 = 0.f, q2 = 0.f, q3 = 0.f;
    for (int q = 0; q < 43; ++q) {
      float4 ff = f4[q];
      q0 = fmaf(ff.x, wp[0],   q0);
      q1 = fmaf(ff.y, wp[128], q1);
      q2 = fmaf(ff.z, wp[256], q2);
      q3 = fmaf(ff.w, wp[384], q3);
      wp += 512;
    }
    float acc = (q0 + q1) + (q2 + q3);
    if (g) fc1p[o] = acc;
    __syncthreads();
    if (!g) a1[o] = fmaxf(acc + fc1p[o] + bfc1[o], 0.f);
  }
  __syncthreads();

  // FC2 (128->4) on one wave: lane = (kk,cls), shuffle-reduce over kk.
  if (t < 64) {
    int cls = t & 3, kk = t >> 2;             // kk 0..15, 8 k's each
    const float* w2p = ws + WS_W2 + cls * 128 + kk * 8;
    const float* av = a1 + kk * 8;
    float p = 0.f;
    #pragma unroll
    for (int i = 0; i < 8; ++i) p = fmaf(av[i], w2p[i], p);
    p += __shfl_down(p, 32);
    p += __shfl_down(p, 16);
    p += __shfl_down(p, 8);
    p += __shfl_down(p, 4);
    if (t < 4) s2[t] = p + bfc2[t];
  }
  __syncthreads();
  // softmax + store
  if (t < 4) {
    float v0 = s2[0], v1 = s2[1], v2 = s2[2], v3 = s2[3];
    float m = fmaxf(fmaxf(v0, v1), fmaxf(v2, v3));
    float e0 = expf(v0 - m), e1 = expf(v1 - m);
    float e2 = expf(v2 - m), e3 = expf(v3 - m);
    float inv = 1.f / (e0 + e1 + e2 + e3);
    float mine = (t == 0) ? e0 : (t == 1) ? e1 : (t == 2) ? e2 : e3;
    out[b * 4 + t] = mine * inv;
  }
}

extern "C" void kernel_launch(void* const* d_in, const int* in_sizes, int n_in,
                              void* d_out, int out_size, void* d_ws, size_t ws_size,
                              hipStream_t stream) {
  const float* x     = (const float*)d_in[0];
  const float* wconv = (const float*)d_in[1];
  const float* bconv = (const float*)d_in[2];
  const float* wfc1  = (const float*)d_in[3];
  const float* bfc1  = (const float*)d_in[4];
  const float* wfc2  = (const float*)d_in[5];
  const float* bfc2  = (const float*)d_in[6];
  float* out = (float*)d_out;
  float* ws  = (float*)d_ws;

  quant_all<<<89, 256, 0, stream>>>(wconv, wfc1, wfc2, ws);
  fused_net<<<2048, 256, 0, stream>>>(x, bconv, ws, bfc1, bfc2, out);
}